// Round 4
// baseline (267.738 us; speedup 1.0000x reference)
//
#include <hip/hip_runtime.h>
#include <hip/hip_bf16.h>

#define B_ 8
#define C_ 128
#define N_ 4096   // H*W = 64*64

typedef __bf16 bf16x8 __attribute__((ext_vector_type(8)));
typedef float  f32x4  __attribute__((ext_vector_type(4)));
typedef unsigned short u16x8 __attribute__((ext_vector_type(8)));

__device__ __forceinline__ float bfu_lo(unsigned u) { unsigned t = u << 16; return __uint_as_float(t); }
__device__ __forceinline__ float bfu_hi(unsigned u) { unsigned t = u & 0xffff0000u; return __uint_as_float(t); }

// ---------------------------------------------------------------------------
// K1: channel softmax over C for each (b, n), x held in registers.
//   xs (fp32, nontemporal -> final output, never re-read) into d_out [b][c][n]
//   vT (bf16) into workspace [b][n][c]
// ---------------------------------------------------------------------------
__global__ __launch_bounds__(128) void chan_softmax(const float* __restrict__ x,
                                                    float* __restrict__ xs,
                                                    __hip_bfloat16* __restrict__ vT)
{
    int idx = blockIdx.x * 128 + threadIdx.x;     // (b, n) flattened, 32768 total
    int b = idx >> 12;
    int n = idx & (N_ - 1);

    const float* xp = x + (size_t)b * C_ * N_ + n;

    float xv[C_];
    #pragma unroll
    for (int c = 0; c < C_; ++c) xv[c] = xp[(size_t)c * N_];   // independent loads

    float m = xv[0];
    #pragma unroll
    for (int c = 1; c < C_; ++c) m = fmaxf(m, xv[c]);

    float s = 0.f;
    #pragma unroll
    for (int c = 0; c < C_; ++c) { xv[c] = __expf(xv[c] - m); s += xv[c]; }
    float inv = 1.f / s;

    float* op = xs + (size_t)b * C_ * N_ + n;
    u16x8* vp = reinterpret_cast<u16x8*>(vT + ((size_t)b * N_ + n) * C_);

    #pragma unroll
    for (int c0 = 0; c0 < C_; c0 += 8) {
        u16x8 pk;
        #pragma unroll
        for (int j = 0; j < 8; ++j) {
            float v = xv[c0 + j] * inv;
            __builtin_nontemporal_store(v, &op[(size_t)(c0 + j) * N_]);
            __hip_bfloat16 hb = __float2bfloat16(v);
            pk[j] = *reinterpret_cast<unsigned short*>(&hb);
        }
        vp[c0 >> 3] = pk;
    }
}

// ---------------------------------------------------------------------------
// K2: S[b][c] = sum_n vT[b][n][c].  One block per batch, no atomics.
// Lane l accumulates channels {2l, 2l+1}; wave w covers 1024 rows.
// ---------------------------------------------------------------------------
__global__ __launch_bounds__(256) void colsum(const __hip_bfloat16* __restrict__ vT,
                                              float* __restrict__ S)
{
    int b    = blockIdx.x;
    int w    = threadIdx.x >> 6;
    int lane = threadIdx.x & 63;
    const unsigned* base = reinterpret_cast<const unsigned*>(vT + (size_t)b * N_ * C_);

    float a0 = 0.f, a1 = 0.f;
    #pragma unroll 8
    for (int r = 0; r < 1024; ++r) {
        unsigned u = base[(size_t)(w * 1024 + r) * (C_ / 2) + lane];  // 2 bf16
        a0 += bfu_lo(u);
        a1 += bfu_hi(u);
    }

    __shared__ float st[4][C_];
    st[w][lane * 2]     = a0;
    st[w][lane * 2 + 1] = a1;
    __syncthreads();
    int t = threadIdx.x;
    if (t < C_)
        S[b * C_ + t] = st[0][t] + st[1][t] + st[2][t] + st[3][t];
}

// ---------------------------------------------------------------------------
// K3: inv[b][i] = 1 / (N + v_i . S)    (first-order softmax denominator;
// exp(e)-1-e <= 0.72 for e in [0,1] bounds attn error <= 1.7e-4, and for the
// actual data the dropped 0.5*sum(e^2) term is ~0.15 of ~4128 -> err ~2e-8).
// ---------------------------------------------------------------------------
__global__ __launch_bounds__(256) void rsum_inv(const __hip_bfloat16* __restrict__ vT,
                                                const float* __restrict__ S,
                                                float* __restrict__ inv)
{
    int idx = blockIdx.x * 256 + threadIdx.x;   // b*N + i
    int b = idx >> 12;
    const u16x8* vp = reinterpret_cast<const u16x8*>(vT + (size_t)idx * C_);
    const float* Sb = S + b * C_;

    float acc = (float)N_;
    #pragma unroll
    for (int j = 0; j < 16; ++j) {
        u16x8 v = vp[j];
        #pragma unroll
        for (int k = 0; k < 8; ++k) {
            unsigned u = (unsigned)v[k] << 16;
            acc += __uint_as_float(u) * Sb[j * 8 + k];
        }
    }
    inv[idx] = 1.0f / acc;
}

// ---------------------------------------------------------------------------
// K4: attention[b][i][j] = exp(<v_i,v_j>) * inv[b][i], single pass, streamed.
// Block owns 64 attention rows; wave w covers col-tiles jt*4+w (64 cols each).
// OPERAND-SWAPPED MFMA: D = mfma(A=col-frags, B=row-frags) so D's reg axis
// walks 4 consecutive attention COLS of one row -> f32x4 nontemporal stores,
// and inv is a per-lane scalar (row = r16 lane index).
// blockIdx&7 = batch pins each batch's 1MB vT panel to one XCD's L2.
// ---------------------------------------------------------------------------
__global__ __launch_bounds__(256, 2) void att_write(const __hip_bfloat16* __restrict__ vT,
                                                    const float* __restrict__ inv,
                                                    float* __restrict__ att)
{
    int bid = blockIdx.x;
    int b   = bid & 7;
    int rowbase = (bid >> 3) * 64;

    int w    = threadIdx.x >> 6;
    int lane = threadIdx.x & 63;
    int r16  = lane & 15;
    int kg   = lane >> 4;

    const __hip_bfloat16* base = vT + (size_t)b * N_ * C_;

    // resident B-operand fragments: the block's 64 attention rows, full K=128
    bf16x8 br[4][4];
    #pragma unroll
    for (int rb = 0; rb < 4; ++rb)
        #pragma unroll
        for (int ks = 0; ks < 4; ++ks)
            br[rb][ks] = *reinterpret_cast<const bf16x8*>(
                base + (size_t)(rowbase + rb * 16 + r16) * C_ + ks * 32 + kg * 8);

    float invr[4];
    #pragma unroll
    for (int rb = 0; rb < 4; ++rb)
        invr[rb] = inv[(size_t)b * N_ + rowbase + rb * 16 + r16];

    float* ab = att + (size_t)b * N_ * N_;

    #pragma unroll 1
    for (int jt = 0; jt < 16; ++jt) {
        int col0 = (jt * 4 + w) * 64;
        f32x4 acc[4][4] = {};                 // [cb][rb]
        #pragma unroll
        for (int ks = 0; ks < 4; ++ks) {
            bf16x8 a[4];
            #pragma unroll
            for (int cb = 0; cb < 4; ++cb)
                a[cb] = *reinterpret_cast<const bf16x8*>(
                    base + (size_t)(col0 + cb * 16 + r16) * C_ + ks * 32 + kg * 8);
            #pragma unroll
            for (int cb = 0; cb < 4; ++cb)
                #pragma unroll
                for (int rb = 0; rb < 4; ++rb)
                    acc[cb][rb] = __builtin_amdgcn_mfma_f32_16x16x32_bf16(
                        a[cb], br[rb][ks], acc[cb][rb], 0, 0, 0);
        }
        // D[m][n]: m (kg*4+r) = col-within-tile (A side), n (r16) = row (B side)
        #pragma unroll
        for (int cb = 0; cb < 4; ++cb)
            #pragma unroll
            for (int rb = 0; rb < 4; ++rb) {
                int row = rowbase + rb * 16 + r16;
                int col = col0 + cb * 16 + kg * 4;
                f32x4 o;
                #pragma unroll
                for (int r = 0; r < 4; ++r)
                    o[r] = __expf(acc[cb][rb][r]) * invr[rb];
                __builtin_nontemporal_store(o,
                    reinterpret_cast<f32x4*>(&ab[(size_t)row * N_ + col]));
            }
    }
}

// ---------------------------------------------------------------------------
// K5: out = gamma * (V @ attention^T) + xs. gamma==0 in the benchmark ->
// immediate exit; general path is a correct fallback.
// ---------------------------------------------------------------------------
__global__ __launch_bounds__(128) void pv_update(const float* __restrict__ gamma,
                                                 const __hip_bfloat16* __restrict__ vT,
                                                 const float* __restrict__ att,
                                                 float* __restrict__ out)
{
    float g = gamma[0];
    if (g == 0.0f) return;

    int b = blockIdx.y;
    int n = blockIdx.x;
    int c = threadIdx.x;   // 128

    const float* arow = att + ((size_t)b * N_ + n) * N_;
    const __hip_bfloat16* vb = vT + (size_t)b * N_ * C_;

    float acc = 0.f;
    for (int m = 0; m < N_; ++m)
        acc += __bfloat162float(vb[(size_t)m * C_ + c]) * arow[m];

    size_t oi = ((size_t)b * C_ + c) * N_ + n;
    out[oi] = g * acc + out[oi];
}

// ---------------------------------------------------------------------------
extern "C" void kernel_launch(void* const* d_in, const int* in_sizes, int n_in,
                              void* d_out, int out_size, void* d_ws, size_t ws_size,
                              hipStream_t stream)
{
    const float* x     = (const float*)d_in[0];
    const float* gamma = (const float*)d_in[1];

    float* out = (float*)d_out;                        // [B][C][N]  (4,194,304 f32)
    float* att = out + (size_t)B_ * C_ * N_;           // [B][N][N]  (134,217,728 f32)
    __hip_bfloat16* vT = (__hip_bfloat16*)d_ws;        // [B][N][C]  bf16, 8 MB
    float* S   = (float*)(vT + (size_t)B_ * N_ * C_);  // [B][C] f32, 4 KB
    float* inv = S + B_ * C_;                          // [B][N] f32, 128 KB

    chan_softmax<<<(B_ * N_) / 128, 128, 0, stream>>>(x, out, vT);
    colsum<<<B_, 256, 0, stream>>>(vT, S);
    rsum_inv<<<(B_ * N_) / 256, 256, 0, stream>>>(vT, S, inv);
    att_write<<<(N_ / 64) * B_, 256, 0, stream>>>(vT, inv, att);
    pv_update<<<dim3(N_, B_), C_, 0, stream>>>(gamma, vT, att, out);
}

// Round 5
// 214.791 us; speedup vs baseline: 1.2465x; 1.2465x over previous
//
#include <hip/hip_runtime.h>
#include <hip/hip_bf16.h>

#define B_ 8
#define C_ 128
#define N_ 4096   // H*W = 64*64

typedef __bf16 bf16x8 __attribute__((ext_vector_type(8)));
typedef float  f32x4  __attribute__((ext_vector_type(4)));
typedef unsigned short u16x8 __attribute__((ext_vector_type(8)));

__device__ __forceinline__ float bfu_lo(unsigned u) { unsigned t = u << 16; return __uint_as_float(t); }
__device__ __forceinline__ float bfu_hi(unsigned u) { unsigned t = u & 0xffff0000u; return __uint_as_float(t); }

// ---------------------------------------------------------------------------
// K1: channel softmax over C for each (b, n), x held in registers.
//   xs (fp32) into d_out [b][c][n]   (final output when gamma==0)
//   vT (bf16) into workspace [b][n][c]
// Plain stores (NT hint suspected harmful in R4's A/B history).
// ---------------------------------------------------------------------------
__global__ __launch_bounds__(256) void chan_softmax(const float* __restrict__ x,
                                                    float* __restrict__ xs,
                                                    __hip_bfloat16* __restrict__ vT)
{
    int idx = blockIdx.x * 256 + threadIdx.x;     // (b, n) flattened, 32768 total
    int b = idx >> 12;
    int n = idx & (N_ - 1);

    const float* xp = x + (size_t)b * C_ * N_ + n;

    float xv[C_];
    #pragma unroll
    for (int c = 0; c < C_; ++c) xv[c] = xp[(size_t)c * N_];   // independent loads

    float m = xv[0];
    #pragma unroll
    for (int c = 1; c < C_; ++c) m = fmaxf(m, xv[c]);

    float s = 0.f;
    #pragma unroll
    for (int c = 0; c < C_; ++c) { xv[c] = __expf(xv[c] - m); s += xv[c]; }
    float inv = 1.f / s;

    float* op = xs + (size_t)b * C_ * N_ + n;
    u16x8* vp = reinterpret_cast<u16x8*>(vT + ((size_t)b * N_ + n) * C_);

    #pragma unroll
    for (int c0 = 0; c0 < C_; c0 += 8) {
        u16x8 pk;
        #pragma unroll
        for (int j = 0; j < 8; ++j) {
            float v = xv[c0 + j] * inv;
            op[(size_t)(c0 + j) * N_] = v;
            __hip_bfloat16 hb = __float2bfloat16(v);
            pk[j] = *reinterpret_cast<unsigned short*>(&hb);
        }
        vp[c0 >> 3] = pk;
    }
}

// ---------------------------------------------------------------------------
// K2: S[b][c] = sum_n vT[b][n][c].  One block per batch, no atomics.
// ---------------------------------------------------------------------------
__global__ __launch_bounds__(256) void colsum(const __hip_bfloat16* __restrict__ vT,
                                              float* __restrict__ S)
{
    int b    = blockIdx.x;
    int w    = threadIdx.x >> 6;
    int lane = threadIdx.x & 63;
    const unsigned* base = reinterpret_cast<const unsigned*>(vT + (size_t)b * N_ * C_);

    float a0 = 0.f, a1 = 0.f;
    #pragma unroll 8
    for (int r = 0; r < 1024; ++r) {
        unsigned u = base[(size_t)(w * 1024 + r) * (C_ / 2) + lane];  // 2 bf16
        a0 += bfu_lo(u);
        a1 += bfu_hi(u);
    }

    __shared__ float st[4][C_];
    st[w][lane * 2]     = a0;
    st[w][lane * 2 + 1] = a1;
    __syncthreads();
    int t = threadIdx.x;
    if (t < C_)
        S[b * C_ + t] = st[0][t] + st[1][t] + st[2][t] + st[3][t];
}

// ---------------------------------------------------------------------------
// K3: inv[b][i] = 1 / (N + v_i . S)   (first-order softmax denominator,
// validated R4: absmax 4.9e-4 vs 9.5e-3 threshold).
// ---------------------------------------------------------------------------
__global__ __launch_bounds__(256) void rsum_inv(const __hip_bfloat16* __restrict__ vT,
                                                const float* __restrict__ S,
                                                float* __restrict__ inv)
{
    int idx = blockIdx.x * 256 + threadIdx.x;   // b*N + i
    int b = idx >> 12;
    const u16x8* vp = reinterpret_cast<const u16x8*>(vT + (size_t)idx * C_);
    const float* Sb = S + b * C_;

    float acc = (float)N_;
    #pragma unroll
    for (int j = 0; j < 16; ++j) {
        u16x8 v = vp[j];
        #pragma unroll
        for (int k = 0; k < 8; ++k) {
            unsigned u = (unsigned)v[k] << 16;
            acc += __uint_as_float(u) * Sb[j * 8 + k];
        }
    }
    inv[idx] = 1.0f / acc;
}

// ---------------------------------------------------------------------------
// K4: attention[b][i][j] = exp(<v_i,v_j>) * inv[b][i].
// EXACTLY R2's pass-2: 64-row stripe per block, 4 waves = 4 column windows,
// A-fragments register-resident, plain scalar stores, LB(256,2).
// Only change vs R2: inv comes from K3 instead of an in-kernel pass 1.
// ---------------------------------------------------------------------------
__global__ __launch_bounds__(256, 2) void att_write(const __hip_bfloat16* __restrict__ vT,
                                                    const float* __restrict__ inv,
                                                    float* __restrict__ att)
{
    int bid = blockIdx.x;
    int b = bid & 7;                       // batch pinned to XCD
    int rowbase = (bid >> 3) * 64;

    int w    = threadIdx.x >> 6;           // wave id: column window within tile
    int lane = threadIdx.x & 63;
    int r16  = lane & 15;
    int kg   = lane >> 4;

    const __hip_bfloat16* base = vT + (size_t)b * N_ * C_;

    // A fragments: rows rowbase..rowbase+63, full K=128. 16 x bf16x8 = 64 VGPR.
    bf16x8 a[4][4];
    #pragma unroll
    for (int mi = 0; mi < 4; ++mi)
        #pragma unroll
        for (int ks = 0; ks < 4; ++ks)
            a[mi][ks] = *reinterpret_cast<const bf16x8*>(
                base + (size_t)(rowbase + mi * 16 + r16) * C_ + ks * 32 + kg * 8);

    float invr[4][4];
    #pragma unroll
    for (int mi = 0; mi < 4; ++mi)
        #pragma unroll
        for (int r = 0; r < 4; ++r)
            invr[mi][r] = inv[(size_t)b * N_ + rowbase + mi * 16 + kg * 4 + r];

    float* ab = att + (size_t)b * N_ * N_;

    #pragma unroll 1
    for (int jt = 0; jt < 16; ++jt) {
        int colbase = jt * 256 + w * 64;
        f32x4 acc[4][4] = {};
        #pragma unroll
        for (int ks = 0; ks < 4; ++ks) {
            bf16x8 bb[4];
            #pragma unroll
            for (int nj = 0; nj < 4; ++nj)
                bb[nj] = *reinterpret_cast<const bf16x8*>(
                    base + (size_t)(colbase + nj * 16 + r16) * C_ + ks * 32 + kg * 8);
            #pragma unroll
            for (int mi = 0; mi < 4; ++mi)
                #pragma unroll
                for (int nj = 0; nj < 4; ++nj)
                    acc[mi][nj] = __builtin_amdgcn_mfma_f32_16x16x32_bf16(
                        a[mi][ks], bb[nj], acc[mi][nj], 0, 0, 0);
        }
        #pragma unroll
        for (int mi = 0; mi < 4; ++mi) {
            int row = rowbase + mi * 16 + kg * 4;
            #pragma unroll
            for (int nj = 0; nj < 4; ++nj) {
                int col = colbase + nj * 16 + r16;
                #pragma unroll
                for (int r = 0; r < 4; ++r)
                    ab[(size_t)(row + r) * N_ + col] = __expf(acc[mi][nj][r]) * invr[mi][r];
            }
        }
    }
}

// ---------------------------------------------------------------------------
// K5: out = gamma * (V @ attention^T) + xs. gamma==0 in the benchmark ->
// immediate exit; general path is a correct fallback.
// ---------------------------------------------------------------------------
__global__ __launch_bounds__(128) void pv_update(const float* __restrict__ gamma,
                                                 const __hip_bfloat16* __restrict__ vT,
                                                 const float* __restrict__ att,
                                                 float* __restrict__ out)
{
    float g = gamma[0];
    if (g == 0.0f) return;

    int b = blockIdx.y;
    int n = blockIdx.x;
    int c = threadIdx.x;   // 128

    const float* arow = att + ((size_t)b * N_ + n) * N_;
    const __hip_bfloat16* vb = vT + (size_t)b * N_ * C_;

    float acc = 0.f;
    for (int m = 0; m < N_; ++m)
        acc += __bfloat162float(vb[(size_t)m * C_ + c]) * arow[m];

    size_t oi = ((size_t)b * C_ + c) * N_ + n;
    out[oi] = g * acc + out[oi];
}

// ---------------------------------------------------------------------------
extern "C" void kernel_launch(void* const* d_in, const int* in_sizes, int n_in,
                              void* d_out, int out_size, void* d_ws, size_t ws_size,
                              hipStream_t stream)
{
    const float* x     = (const float*)d_in[0];
    const float* gamma = (const float*)d_in[1];

    float* out = (float*)d_out;                        // [B][C][N]  (4,194,304 f32)
    float* att = out + (size_t)B_ * C_ * N_;           // [B][N][N]  (134,217,728 f32)
    __hip_bfloat16* vT = (__hip_bfloat16*)d_ws;        // [B][N][C]  bf16, 8 MB
    float* S   = (float*)(vT + (size_t)B_ * N_ * C_);  // [B][C] f32, 4 KB
    float* inv = S + B_ * C_;                          // [B][N] f32, 128 KB

    chan_softmax<<<(B_ * N_) / 256, 256, 0, stream>>>(x, out, vT);
    colsum<<<B_, 256, 0, stream>>>(vT, S);
    rsum_inv<<<(B_ * N_) / 256, 256, 0, stream>>>(vT, S, inv);
    att_write<<<(N_ / 64) * B_, 256, 0, stream>>>(vT, inv, att);
    pv_update<<<dim3(N_, B_), C_, 0, stream>>>(gamma, vT, att, out);
}

// Round 6
// 158.833 us; speedup vs baseline: 1.6857x; 1.3523x over previous
//
#include <hip/hip_runtime.h>
#include <hip/hip_bf16.h>

#define B_ 8
#define C_ 128
#define N_ 4096   // H*W = 64*64

typedef __bf16 bf16x8 __attribute__((ext_vector_type(8)));
typedef float  f32x4  __attribute__((ext_vector_type(4)));
typedef unsigned short u16x8 __attribute__((ext_vector_type(8)));

__device__ __forceinline__ float bfu_lo(unsigned u) { unsigned t = u << 16; return __uint_as_float(t); }
__device__ __forceinline__ float bfu_hi(unsigned u) { unsigned t = u & 0xffff0000u; return __uint_as_float(t); }

// ---------------------------------------------------------------------------
// K1: channel softmax over C for each (b, n), x held in registers.
//   xs (fp32) into d_out [b][c][n]   (final output when gamma==0)
//   vT (bf16) into workspace [b][n][c]
// Also zeroes S (colsum accumulator) — runs before colsum on the stream.
// ---------------------------------------------------------------------------
__global__ __launch_bounds__(256) void chan_softmax(const float* __restrict__ x,
                                                    float* __restrict__ xs,
                                                    __hip_bfloat16* __restrict__ vT,
                                                    float* __restrict__ S)
{
    int idx = blockIdx.x * 256 + threadIdx.x;     // (b, n) flattened, 32768 total
    if (idx < B_ * C_) S[idx] = 0.0f;

    int b = idx >> 12;
    int n = idx & (N_ - 1);

    const float* xp = x + (size_t)b * C_ * N_ + n;

    float xv[C_];
    #pragma unroll
    for (int c = 0; c < C_; ++c) xv[c] = xp[(size_t)c * N_];   // independent loads

    float m = xv[0];
    #pragma unroll
    for (int c = 1; c < C_; ++c) m = fmaxf(m, xv[c]);

    float s = 0.f;
    #pragma unroll
    for (int c = 0; c < C_; ++c) { xv[c] = __expf(xv[c] - m); s += xv[c]; }
    float inv = 1.f / s;

    float* op = xs + (size_t)b * C_ * N_ + n;
    u16x8* vp = reinterpret_cast<u16x8*>(vT + ((size_t)b * N_ + n) * C_);

    #pragma unroll
    for (int c0 = 0; c0 < C_; c0 += 8) {
        u16x8 pk;
        #pragma unroll
        for (int j = 0; j < 8; ++j) {
            float v = xv[c0 + j] * inv;
            op[(size_t)(c0 + j) * N_] = v;
            __hip_bfloat16 hb = __float2bfloat16(v);
            pk[j] = *reinterpret_cast<unsigned short*>(&hb);
        }
        vp[c0 >> 3] = pk;
    }
}

// ---------------------------------------------------------------------------
// K2: S[b][c] += partial column sums of vT.  256 blocks (32 per batch, 128
// rows each) -> fully parallel, tiny atomic tail (32 adds per address).
// ---------------------------------------------------------------------------
__global__ __launch_bounds__(256) void colsum(const __hip_bfloat16* __restrict__ vT,
                                              float* __restrict__ S)
{
    int bid   = blockIdx.x;
    int b     = bid & 7;
    int chunk = bid >> 3;                 // 0..31
    int w     = threadIdx.x >> 6;
    int lane  = threadIdx.x & 63;

    const unsigned* base = reinterpret_cast<const unsigned*>(vT + (size_t)b * N_ * C_)
                         + (size_t)(chunk * 128 + w * 32) * (C_ / 2) + lane;

    float a0 = 0.f, a1 = 0.f;
    #pragma unroll 8
    for (int r = 0; r < 32; ++r) {
        unsigned u = base[(size_t)r * (C_ / 2)];  // 2 bf16
        a0 += bfu_lo(u);
        a1 += bfu_hi(u);
    }

    __shared__ float st[4][C_];
    st[w][lane * 2]     = a0;
    st[w][lane * 2 + 1] = a1;
    __syncthreads();
    int t = threadIdx.x;
    if (t < C_)
        atomicAdd(&S[b * C_ + t], st[0][t] + st[1][t] + st[2][t] + st[3][t]);
}

// ---------------------------------------------------------------------------
// K3: attention[b][i][j] = exp(<v_i,v_j>) * inv_i, single pass.
// Same compute structure as the known-good R2/R5 kernel (64-row stripe per
// block, 4 column-window waves, A-frags register-resident). Changes:
//  - inv computed IN-KERNEL: inv_i = 1/(N + v_i.S) from the A-frags (first-
//    order denominator, validated R4/R5 at absmax 4.9e-4).
//  - stores staged through per-wave private LDS [64][68] so each global store
//    is dwordx4 covering 4 rows x 256 B contiguous (16 instrs/jt/wave vs 256
//    scalar). Plain stores (NT proven harmful in R4).
// ---------------------------------------------------------------------------
__global__ __launch_bounds__(256, 2) void att_write(const __hip_bfloat16* __restrict__ vT,
                                                    const float* __restrict__ S,
                                                    float* __restrict__ att)
{
    __shared__ float lds[4][64][68];      // per-wave [64][68] padded tiles

    int bid = blockIdx.x;
    int b = bid & 7;                       // batch pinned to XCD
    int rowbase = (bid >> 3) * 64;

    int w    = threadIdx.x >> 6;           // wave id: column window within tile
    int lane = threadIdx.x & 63;
    int r16  = lane & 15;
    int kg   = lane >> 4;

    const __hip_bfloat16* base = vT + (size_t)b * N_ * C_;

    // A fragments: rows rowbase..rowbase+63, full K=128. 16 x bf16x8 = 64 VGPR.
    bf16x8 a[4][4];
    #pragma unroll
    for (int mi = 0; mi < 4; ++mi)
        #pragma unroll
        for (int ks = 0; ks < 4; ++ks)
            a[mi][ks] = *reinterpret_cast<const bf16x8*>(
                base + (size_t)(rowbase + mi * 16 + r16) * C_ + ks * 32 + kg * 8);

    // inv_i = 1/(N + v_i.S): dot from A-frags, reduce over the 4 kg lanes.
    // After reduce, lane with r16 = q holds inv for row mi*16+q.
    const float* Sb = S + b * C_;
    float inv_src[4];
    #pragma unroll
    for (int mi = 0; mi < 4; ++mi) {
        float d = 0.f;
        #pragma unroll
        for (int ks = 0; ks < 4; ++ks) {
            int k0 = ks * 32 + kg * 8;
            #pragma unroll
            for (int j = 0; j < 8; ++j)
                d += (float)a[mi][ks][j] * Sb[k0 + j];
        }
        d += __shfl_xor(d, 16, 64);
        d += __shfl_xor(d, 32, 64);
        inv_src[mi] = 1.0f / ((float)N_ + d);
    }

    float* ab = att + (size_t)b * N_ * N_;
    float* myl = &lds[w][0][0];

    #pragma unroll 1
    for (int jt = 0; jt < 16; ++jt) {
        int colbase = jt * 256 + w * 64;
        f32x4 acc[4][4] = {};
        #pragma unroll
        for (int ks = 0; ks < 4; ++ks) {
            bf16x8 bb[4];
            #pragma unroll
            for (int nj = 0; nj < 4; ++nj)
                bb[nj] = *reinterpret_cast<const bf16x8*>(
                    base + (size_t)(colbase + nj * 16 + r16) * C_ + ks * 32 + kg * 8);
            #pragma unroll
            for (int mi = 0; mi < 4; ++mi)
                #pragma unroll
                for (int nj = 0; nj < 4; ++nj)
                    acc[mi][nj] = __builtin_amdgcn_mfma_f32_16x16x32_bf16(
                        a[mi][ks], bb[nj], acc[mi][nj], 0, 0, 0);
        }

        // stage raw acc into private LDS: L[row][col], row=mi*16+kg*4+r, col=nj*16+r16
        #pragma unroll
        for (int mi = 0; mi < 4; ++mi)
            #pragma unroll
            for (int nj = 0; nj < 4; ++nj)
                #pragma unroll
                for (int r = 0; r < 4; ++r)
                    myl[(mi * 16 + kg * 4 + r) * 68 + nj * 16 + r16] = acc[mi][nj][r];

        asm volatile("s_waitcnt lgkmcnt(0)" ::: "memory");
        __builtin_amdgcn_sched_barrier(0);

        // readback row-major: lane covers row p*4+kg, cols 4*r16..+3 -> dwordx4
        // global stores, 4 rows x 256 B contiguous per instruction.
        #pragma unroll
        for (int p = 0; p < 16; ++p) {
            int row = p * 4 + kg;                       // 0..63
            f32x4 o = *reinterpret_cast<f32x4*>(myl + row * 68 + 4 * r16);
            float iv = __shfl(inv_src[p >> 2], ((p * 4) & 15) + kg, 64);
            #pragma unroll
            for (int i = 0; i < 4; ++i) o[i] = __expf(o[i]) * iv;
            *reinterpret_cast<f32x4*>(&ab[(size_t)(rowbase + row) * N_ + colbase + 4 * r16]) = o;
        }
    }
}

// ---------------------------------------------------------------------------
// K4: out = gamma * (V @ attention^T) + xs. gamma==0 in the benchmark ->
// immediate exit; general path is a correct fallback.
// ---------------------------------------------------------------------------
__global__ __launch_bounds__(128) void pv_update(const float* __restrict__ gamma,
                                                 const __hip_bfloat16* __restrict__ vT,
                                                 const float* __restrict__ att,
                                                 float* __restrict__ out)
{
    float g = gamma[0];
    if (g == 0.0f) return;

    int b = blockIdx.y;
    int n = blockIdx.x;
    int c = threadIdx.x;   // 128

    const float* arow = att + ((size_t)b * N_ + n) * N_;
    const __hip_bfloat16* vb = vT + (size_t)b * N_ * C_;

    float acc = 0.f;
    for (int m = 0; m < N_; ++m)
        acc += __bfloat162float(vb[(size_t)m * C_ + c]) * arow[m];

    size_t oi = ((size_t)b * C_ + c) * N_ + n;
    out[oi] = g * acc + out[oi];
}

// ---------------------------------------------------------------------------
extern "C" void kernel_launch(void* const* d_in, const int* in_sizes, int n_in,
                              void* d_out, int out_size, void* d_ws, size_t ws_size,
                              hipStream_t stream)
{
    const float* x     = (const float*)d_in[0];
    const float* gamma = (const float*)d_in[1];

    float* out = (float*)d_out;                        // [B][C][N]  (4,194,304 f32)
    float* att = out + (size_t)B_ * C_ * N_;           // [B][N][N]  (134,217,728 f32)
    __hip_bfloat16* vT = (__hip_bfloat16*)d_ws;        // [B][N][C]  bf16, 8 MB
    float* S   = (float*)(vT + (size_t)B_ * N_ * C_);  // [B][C] f32, 4 KB

    chan_softmax<<<(B_ * N_) / 256, 256, 0, stream>>>(x, out, vT, S);
    colsum<<<256, 256, 0, stream>>>(vT, S);
    att_write<<<(N_ / 64) * B_, 256, 0, stream>>>(vT, S, att);
    pv_update<<<dim3(N_, B_), C_, 0, stream>>>(gamma, vT, att, out);
}